// Round 6
// baseline (220.875 us; speedup 1.0000x reference)
//
#include <hip/hip_runtime.h>
#include <stdint.h>

// Problem constants (fixed by setup_inputs in the reference)
#define BATCH 32
#define HDIM  1024
#define WDIM  1024
#define H2    (HDIM / 2)
#define W2    (WDIM / 2)
#define NSTN  256                 // stations per batch
#define NBLOCKS 2048              // 16384 yp-pairs / 8 per block

// ---------------------------------------------------------------------------
// Wave-64 + LDS block reduction (sum). Block size = 256. Result in thread 0.
// ---------------------------------------------------------------------------
__device__ __forceinline__ float blockReduceSum(float v, float* smem) {
    #pragma unroll
    for (int off = 32; off > 0; off >>= 1)
        v += __shfl_down(v, off, 64);
    const int lane = threadIdx.x & 63;
    const int wid  = threadIdx.x >> 6;
    if (lane == 0) smem[wid] = v;
    __syncthreads();
    v = (threadIdx.x < 4) ? smem[threadIdx.x] : 0.0f;
    if (wid == 0) {
        v += __shfl_down(v, 2, 64);
        v += __shfl_down(v, 1, 64);
    }
    return v;
}

// ---------------------------------------------------------------------------
// Kernel A: image MSE partials (all blocks) + station MSE partials (blocks
// 0..31). Partials to unique d_ws slots (no atomics/fences — round-2 lesson).
//
// Round-6 structure: BLOCK-CONTIGUOUS STREAMING. Flat row-pair id
// q in [0,16384); block g owns q in [8g, 8g+8) — a contiguous 64 KB pred
// slab within ONE batch (512 pairs/batch = 64 blocks/batch, boundaries
// align). Each iteration i processes 2 pairs: q = 8g + 2i + (tid>>7);
// 128 threads x 8 px cover a full 1024-px row pair. Consecutive iterations
// are adjacent in memory -> ~2 long sequential DRAM streams per block
// (rounds 3-5 had ~20 short scattered streams per WAVE: batch-interleaved
// unit order; totals were stuck at ~63-70us kernel vs 25us traffic floor).
// Tgt rows (yp-1, yp, yp+1) overlap 2/3 between iterations -> L1 reuse.
//
// Per 8x2-px tile: 4 pred float4 + 3 tgt float4 + 6 clamped scalar edge
// loads. No shuffles, no divergent patches (round-4 lesson).
//
// jax.image.resize 'bilinear' 512->1024 (half-pixel centers):
//   even y=2m:  0.25*t[m-1] + 0.75*t[m]   (index-clamped == edge renorm)
//   odd  y=2m+1: 0.75*t[m] + 0.25*t[m+1]  (same in x)
// ---------------------------------------------------------------------------
__global__ __launch_bounds__(256) void fused_compute_kernel(
        const float* __restrict__ pred,
        const float* __restrict__ tgt,
        const int*   __restrict__ pos,
        const float* __restrict__ runoff,
        float* __restrict__ img_part,    // [NBLOCKS]
        float* __restrict__ stn_part) {  // [32]
    __shared__ float smem[4];

    // ---- station partial (blocks 0..31, one thread per station) ----
    if (blockIdx.x < 32) {
        const int idx = blockIdx.x * 256 + threadIdx.x;   // 32*256 = B*S
        const int bb = idx >> 8;                          // NSTN = 256
        const int px = pos[idx * 2 + 0];
        const int py = pos[idx * 2 + 1];
        const float* p = pred + ((int64_t)bb << 20);
        float sum = 0.0f; int cnt = 0;
        #pragma unroll
        for (int dy = -1; dy <= 1; ++dy) {
            const int y = py + dy;
            if (y < 0 || y >= HDIM) continue;
            #pragma unroll
            for (int dx = -1; dx <= 1; ++dx) {
                const int x = px + dx;
                if (x < 0 || x >= WDIM) continue;
                sum += p[y * WDIM + x];
                cnt++;
            }
        }
        const float d = sum / (float)cnt - runoff[idx];
        const float bs = blockReduceSum(d * d, smem);
        if (threadIdx.x == 0) stn_part[blockIdx.x] = bs;
        __syncthreads();   // smem reuse hazard before img reduction
    }

    // ---- image loss: 4 iterations over a contiguous 8-pair slab ----
    const int xg   = threadIdx.x & 127;   // 8-px x-group (wave-contiguous)
    const int half = threadIdx.x >> 7;    // which of the 2 pairs this iter
    const int x0 = xg << 3;
    const int m0 = xg << 2;
    const int xm1 = (m0 == 0)         ? 0      : m0 - 1;
    const int xp4 = (m0 + 4 > W2 - 1) ? W2 - 1 : m0 + 4;

    const int qbase = (blockIdx.x << 3) + half;   // flat pair id, +2 per iter
    const int bb    = qbase >> 9;                 // batch (constant: slab
    const int ypb   = qbase & 511;                //  never crosses batches)
    const float* predb = pred + ((int64_t)bb << 20);
    const float* tgtb  = tgt  + ((int64_t)bb << 18);

    float img_local = 0.0f;
    #pragma unroll 2
    for (int i = 0; i < 4; ++i) {
        const int yp = ypb + 2 * i;
        const int ym1 = (yp == 0)      ? 0      : yp - 1;
        const int yp1 = (yp == H2 - 1) ? H2 - 1 : yp + 1;

        const float* pr = predb + (yp << 11) + x0;     // row 2*yp
        const float4 pe0 = ((const float4*)pr)[0];
        const float4 pe1 = ((const float4*)pr)[1];
        const float4 po0 = ((const float4*)(pr + WDIM))[0];  // row 2*yp+1
        const float4 po1 = ((const float4*)(pr + WDIM))[1];

        const float* tA = tgtb + (ym1 << 9);
        const float* tB = tgtb + (yp  << 9);
        const float* tC = tgtb + (yp1 << 9);

        const float4 a4 = *(const float4*)(tA + m0);
        const float4 b4 = *(const float4*)(tB + m0);
        const float4 c4 = *(const float4*)(tC + m0);
        const float la = tA[xm1], ra = tA[xp4];
        const float lb = tB[xm1], rb = tB[xp4];
        const float lc = tC[xm1], rc = tC[xp4];

        // vertical interp across the 6-column window [m0-1 .. m0+4]
        float e[6], o[6];
        e[0] = 0.25f * la   + 0.75f * lb;    o[0] = 0.75f * lb   + 0.25f * lc;
        e[1] = 0.25f * a4.x + 0.75f * b4.x;  o[1] = 0.75f * b4.x + 0.25f * c4.x;
        e[2] = 0.25f * a4.y + 0.75f * b4.y;  o[2] = 0.75f * b4.y + 0.25f * c4.y;
        e[3] = 0.25f * a4.z + 0.75f * b4.z;  o[3] = 0.75f * b4.z + 0.25f * c4.z;
        e[4] = 0.25f * a4.w + 0.75f * b4.w;  o[4] = 0.75f * b4.w + 0.25f * c4.w;
        e[5] = 0.25f * ra   + 0.75f * rb;    o[5] = 0.75f * rb   + 0.25f * rc;

        const float pev[8] = {pe0.x, pe0.y, pe0.z, pe0.w, pe1.x, pe1.y, pe1.z, pe1.w};
        const float pov[8] = {po0.x, po0.y, po0.z, po0.w, po1.x, po1.y, po1.z, po1.w};

        // horizontal interp (even,odd per m-col) + squared diff, 16 pixels
        #pragma unroll
        for (int k = 0; k < 4; ++k) {
            const float te0 = 0.25f * e[k]     + 0.75f * e[k + 1];
            const float te1 = 0.75f * e[k + 1] + 0.25f * e[k + 2];
            const float to0 = 0.25f * o[k]     + 0.75f * o[k + 1];
            const float to1 = 0.75f * o[k + 1] + 0.25f * o[k + 2];
            const float d0 = pev[2 * k]     - te0;
            const float d1 = pev[2 * k + 1] - te1;
            const float d2 = pov[2 * k]     - to0;
            const float d3 = pov[2 * k + 1] - to1;
            img_local += d0 * d0 + d1 * d1 + d2 * d2 + d3 * d3;
        }
    }

    const float bi = blockReduceSum(img_local, smem);
    if (threadIdx.x == 0) img_part[blockIdx.x] = bi;
}

// ---------------------------------------------------------------------------
// Kernel B: reduce 2048 img partials + 32 stn partials, write 3 outputs.
// ---------------------------------------------------------------------------
__global__ __launch_bounds__(256) void finalize_kernel(
        const float* __restrict__ img_part,
        const float* __restrict__ stn_part,
        float* __restrict__ out) {
    __shared__ float smem[4];

    float v = 0.0f;
    #pragma unroll
    for (int i = 0; i < NBLOCKS / 256; ++i)
        v += img_part[threadIdx.x + i * 256];
    const float img_sum = blockReduceSum(v, smem);
    __syncthreads();   // smem reuse

    float s = (threadIdx.x < 32) ? stn_part[threadIdx.x] : 0.0f;
    const float stn_sum = blockReduceSum(s, smem);

    if (threadIdx.x == 0) {
        const float img = img_sum * (1.0f / ((float)BATCH * HDIM * WDIM));
        const float stn = stn_sum * (1.0f / ((float)BATCH * NSTN));
        out[0] = img + 0.5f * stn;   // IMAGE_W=1.0, STATION_W=0.5
        out[1] = img;
        out[2] = stn;
    }
}

extern "C" void kernel_launch(void* const* d_in, const int* in_sizes, int n_in,
                              void* d_out, int out_size, void* d_ws, size_t ws_size,
                              hipStream_t stream) {
    const float* pred   = (const float*)d_in[0];
    const float* tgt    = (const float*)d_in[1];
    const int*   pos    = (const int*)d_in[2];
    const float* runoff = (const float*)d_in[3];
    float* out = (float*)d_out;
    float* img_part = (float*)d_ws;            // [NBLOCKS]
    float* stn_part = img_part + NBLOCKS;      // [32]

    // No memset needed: every partial slot is written unconditionally.
    fused_compute_kernel<<<NBLOCKS, 256, 0, stream>>>(pred, tgt, pos, runoff,
                                                      img_part, stn_part);
    finalize_kernel<<<1, 256, 0, stream>>>(img_part, stn_part, out);
}